// Round 2
// baseline (267.263 us; speedup 1.0000x reference)
//
#include <hip/hip_runtime.h>
#include <math.h>

#define LAMBDA_DAG 0.5f

// -------- Kernel 1: probs (transposed) + BCE per-block partials + acc zeroing --------
__global__ void k_probs_bce(const float* __restrict__ logits,
                            const float* __restrict__ labels,
                            float* __restrict__ pT,        // [C*B] transposed probs
                            float* __restrict__ bce_part,  // [gridDim.x]
                            float* __restrict__ acc,       // [2]: mean-sum, edge-count
                            int B, int C) {
    if (blockIdx.x == 0 && threadIdx.x == 0) { acc[0] = 0.f; acc[1] = 0.f; }
    const int N = B * C;
    float accv = 0.f;
    for (int idx = blockIdx.x * blockDim.x + threadIdx.x; idx < N;
         idx += gridDim.x * blockDim.x) {
        float l = logits[idx];
        float y = labels[idx];
        // logaddexp(0, l) = max(l,0) + log1p(exp(-|l|))
        accv += fmaxf(l, 0.f) + log1pf(expf(-fabsf(l))) - l * y;
        float p = 1.f / (1.f + expf(-l));
        int b = idx / C;
        int c = idx - b * C;
        pT[(size_t)c * B + b] = p;
    }
    __shared__ float sdata[256];
    sdata[threadIdx.x] = accv;
    __syncthreads();
    for (int s = blockDim.x >> 1; s > 0; s >>= 1) {
        if (threadIdx.x < s) sdata[threadIdx.x] += sdata[threadIdx.x + s];
        __syncthreads();
    }
    if (threadIdx.x == 0) bce_part[blockIdx.x] = sdata[0];
}

// -------- Kernel 2: one block per child row; float4 dag scan + float4 hit body ----
__global__ void __launch_bounds__(256) k_dag_rows(
        const float* __restrict__ dag,   // [C*C], row i = parents of i
        const float* __restrict__ pT,    // [C*B]
        float* __restrict__ acc,         // [2]
        int B, int C) {
    const int i = blockIdx.x;
    __shared__ __align__(16) float pi[128];   // B <= 128 (actual 64)
    for (int b = threadIdx.x; b < B; b += blockDim.x)
        pi[b] = pT[(size_t)i * B + b];
    __syncthreads();

    const float* drow = dag + (size_t)i * C;
    const int C4 = C >> 2;
    const int B4 = B >> 2;
    float psum = 0.f, pcnt = 0.f;

    const float4* drow4 = (const float4*)drow;
    const float4* pi4 = (const float4*)pi;
    for (int q = threadIdx.x; q < C4; q += blockDim.x) {
        float4 d4 = drow4[q];
#pragma unroll
        for (int k = 0; k < 4; ++k) {
            float dv = (k == 0) ? d4.x : (k == 1) ? d4.y : (k == 2) ? d4.z : d4.w;
            if (dv > 0.f) {
                const int j = q * 4 + k;
                const float4* pj4 = (const float4*)(pT + (size_t)j * B);
                float s = 0.f;
                for (int h = 0; h < B4; ++h) {
                    float4 pj = pj4[h];
                    float4 pv = pi4[h];
                    float d0 = fmaxf(pv.x - pj.x, 0.f);
                    float d1 = fmaxf(pv.y - pj.y, 0.f);
                    float d2 = fmaxf(pv.z - pj.z, 0.f);
                    float d3 = fmaxf(pv.w - pj.w, 0.f);
                    s += d0 * d0 + d1 * d1 + d2 * d2 + d3 * d3;
                }
                for (int b = B4 * 4; b < B; ++b) {   // batch tail (B%4)
                    float diff = fmaxf(pi[b] - pT[(size_t)j * B + b], 0.f);
                    s += diff * diff;
                }
                psum += s;
                pcnt += 1.f;
            }
        }
    }
    for (int j = C4 * 4 + threadIdx.x; j < C; j += blockDim.x) {  // C tail
        if (drow[j] > 0.f) {
            float s = 0.f;
            for (int b = 0; b < B; ++b) {
                float diff = fmaxf(pi[b] - pT[(size_t)j * B + b], 0.f);
                s += diff * diff;
            }
            psum += s;
            pcnt += 1.f;
        }
    }

    __shared__ float s1[256], s2[256];
    s1[threadIdx.x] = psum;
    s2[threadIdx.x] = pcnt;
    __syncthreads();
    for (int s = blockDim.x >> 1; s > 0; s >>= 1) {
        if (threadIdx.x < s) {
            s1[threadIdx.x] += s1[threadIdx.x + s];
            s2[threadIdx.x] += s2[threadIdx.x + s];
        }
        __syncthreads();
    }
    if (threadIdx.x == 0) {
        float np = s2[0];
        if (np > 0.f) {
            atomicAdd(&acc[0], s1[0] / ((float)B * np));  // term_mean_i
            atomicAdd(&acc[1], np);                       // edge count
        }
    }
}

// -------- Kernel 3: final scalar combine --------
__global__ void k_final(const float* __restrict__ bce_part, int nb,
                        const float* __restrict__ acc,
                        float* __restrict__ out, int B, int C) {
    float bs = 0.f;
    for (int k = threadIdx.x; k < nb; k += blockDim.x) bs += bce_part[k];
    __shared__ float s1[256];
    s1[threadIdx.x] = bs;
    __syncthreads();
    for (int s = blockDim.x >> 1; s > 0; s >>= 1) {
        if (threadIdx.x < s) s1[threadIdx.x] += s1[threadIdx.x + s];
        __syncthreads();
    }
    if (threadIdx.x == 0) {
        float edges = acc[1];
        float penalty = (edges > 0.f) ? (acc[0] / edges) : 0.f;
        out[0] = s1[0] / (float)(B * C) + LAMBDA_DAG * penalty;
    }
}

extern "C" void kernel_launch(void* const* d_in, const int* in_sizes, int n_in,
                              void* d_out, int out_size, void* d_ws, size_t ws_size,
                              hipStream_t stream) {
    const float* logits = (const float*)d_in[0];
    const float* labels = (const float*)d_in[1];
    const float* dag    = (const float*)d_in[2];
    float* out = (float*)d_out;

    const int C = (int)(sqrt((double)in_sizes[2]) + 0.5);
    const int B = in_sizes[0] / C;

    float* ws       = (float*)d_ws;
    float* pT       = ws;                          // C*B floats (float4-aligned)
    float* bce_part = pT + (size_t)C * B;          // NB1 floats
    const int NB1 = 320;
    float* acc      = bce_part + NB1;              // 2 floats

    k_probs_bce<<<NB1, 256, 0, stream>>>(logits, labels, pT, bce_part, acc, B, C);
    k_dag_rows<<<C, 256, 0, stream>>>(dag, pT, acc, B, C);
    k_final<<<1, 256, 0, stream>>>(bce_part, NB1, acc, out, B, C);
}

// Round 3
// 195.288 us; speedup vs baseline: 1.3686x; 1.3686x over previous
//
#include <hip/hip_runtime.h>
#include <math.h>

#define LAMBDA_DAG 0.5f

// -------- Kernel 1: probs (transposed) + BCE partials + zero per_term/npar --------
__global__ void k_probs_bce(const float* __restrict__ logits,
                            const float* __restrict__ labels,
                            float* __restrict__ pT,        // [C*B] transposed probs
                            float* __restrict__ bce_part,  // [gridDim.x]
                            float* __restrict__ per_term,  // [C] -> zeroed here
                            float* __restrict__ npar,      // [C] -> zeroed here
                            int B, int C) {
    const int N = B * C;
    const int stride = gridDim.x * blockDim.x;
    const int t0 = blockIdx.x * blockDim.x + threadIdx.x;

    for (int i = t0; i < C; i += stride) { per_term[i] = 0.f; npar[i] = 0.f; }

    float accv = 0.f;
    for (int idx = t0; idx < N; idx += stride) {
        float l = logits[idx];
        float y = labels[idx];
        // logaddexp(0, l) = max(l,0) + log1p(exp(-|l|))
        accv += fmaxf(l, 0.f) + log1pf(expf(-fabsf(l))) - l * y;
        float p = 1.f / (1.f + expf(-l));
        int b = idx / C;
        int c = idx - b * C;
        pT[(size_t)c * B + b] = p;
    }
    __shared__ float sdata[256];
    sdata[threadIdx.x] = accv;
    __syncthreads();
    for (int s = blockDim.x >> 1; s > 0; s >>= 1) {
        if (threadIdx.x < s) sdata[threadIdx.x] += sdata[threadIdx.x + s];
        __syncthreads();
    }
    if (threadIdx.x == 0) bce_part[blockIdx.x] = sdata[0];
}

// -------- Kernel 2: flat dag scan, one 128-B line per thread --------
// Each thread loads 8 independent float4 (its own cache line), tests mostly-zero
// groups with one compare per float4, and on a hit gathers the two L2-resident
// pT rows. Distributed atomics into per_term[i]/npar[i].
__global__ void __launch_bounds__(256) k_dag_flat(
        const float* __restrict__ dag,   // [C*C] flat
        const float* __restrict__ pT,    // [C*B]
        float* __restrict__ per_term,    // [C]
        float* __restrict__ npar,        // [C]
        int B, int C, int nseg) {
    const int seg = blockIdx.x * blockDim.x + threadIdx.x;
    if (seg >= nseg) return;
    const int base = seg * 32;               // flat float index, fits int32 (25M)
    const float4* dp = (const float4*)(dag + (size_t)base);

    float4 v[8];
#pragma unroll
    for (int h = 0; h < 8; ++h) v[h] = dp[h];   // 8 loads in flight

    const int B4 = B >> 2;
#pragma unroll
    for (int h = 0; h < 8; ++h) {
        float4 d4 = v[h];
        float g = d4.x + d4.y + d4.z + d4.w;    // entries are 0/1
        if (g > 0.f) {
#pragma unroll
            for (int k = 0; k < 4; ++k) {
                float dv = (k == 0) ? d4.x : (k == 1) ? d4.y : (k == 2) ? d4.z : d4.w;
                if (dv > 0.f) {
                    int f = base + h * 4 + k;
                    int i = f / C;              // child row
                    int j = f - i * C;          // parent col
                    const float4* pi4 = (const float4*)(pT + (size_t)i * B);
                    const float4* pj4 = (const float4*)(pT + (size_t)j * B);
                    float s = 0.f;
                    for (int q = 0; q < B4; ++q) {
                        float4 a = pi4[q];
                        float4 b = pj4[q];
                        float d0 = fmaxf(a.x - b.x, 0.f);
                        float d1 = fmaxf(a.y - b.y, 0.f);
                        float d2 = fmaxf(a.z - b.z, 0.f);
                        float d3 = fmaxf(a.w - b.w, 0.f);
                        s += d0 * d0 + d1 * d1 + d2 * d2 + d3 * d3;
                    }
                    for (int b = B4 * 4; b < B; ++b) {   // batch tail
                        float diff = fmaxf(pT[(size_t)i * B + b] - pT[(size_t)j * B + b], 0.f);
                        s += diff * diff;
                    }
                    atomicAdd(&per_term[i], s);
                    atomicAdd(&npar[i], 1.f);
                }
            }
        }
    }
}

// -------- Kernel 3: final scalar reduction --------
__global__ void k_final(const float* __restrict__ per_term,
                        const float* __restrict__ npar,
                        const float* __restrict__ bce_part, int nb,
                        float* __restrict__ out, int B, int C) {
    float bs = 0.f, ps = 0.f, es = 0.f;
    for (int k = threadIdx.x; k < nb; k += blockDim.x) bs += bce_part[k];
    for (int i = threadIdx.x; i < C; i += blockDim.x) {
        float np = npar[i];
        es += np;
        if (np > 0.f) ps += per_term[i] / ((float)B * np);
    }
    __shared__ float s1[256], s2[256], s3[256];
    s1[threadIdx.x] = bs;
    s2[threadIdx.x] = ps;
    s3[threadIdx.x] = es;
    __syncthreads();
    for (int s = blockDim.x >> 1; s > 0; s >>= 1) {
        if (threadIdx.x < s) {
            s1[threadIdx.x] += s1[threadIdx.x + s];
            s2[threadIdx.x] += s2[threadIdx.x + s];
            s3[threadIdx.x] += s3[threadIdx.x + s];
        }
        __syncthreads();
    }
    if (threadIdx.x == 0) {
        float penalty = (s3[0] > 0.f) ? (s2[0] / s3[0]) : 0.f;
        out[0] = s1[0] / (float)(B * C) + LAMBDA_DAG * penalty;
    }
}

extern "C" void kernel_launch(void* const* d_in, const int* in_sizes, int n_in,
                              void* d_out, int out_size, void* d_ws, size_t ws_size,
                              hipStream_t stream) {
    const float* logits = (const float*)d_in[0];
    const float* labels = (const float*)d_in[1];
    const float* dag    = (const float*)d_in[2];
    float* out = (float*)d_out;

    const int C = (int)(sqrt((double)in_sizes[2]) + 0.5);
    const int B = in_sizes[0] / C;
    const int CC = in_sizes[2];

    float* ws       = (float*)d_ws;
    float* pT       = ws;                          // C*B floats (16B-aligned)
    float* per_term = pT + (size_t)C * B;          // C
    float* nparw    = per_term + C;                // C
    float* bce_part = nparw + C;                   // NB1
    const int NB1 = 320;

    k_probs_bce<<<NB1, 256, 0, stream>>>(logits, labels, pT, bce_part,
                                         per_term, nparw, B, C);

    const int nseg = (CC + 31) / 32;               // 781250 for C=5000
    const int nblk = (nseg + 255) / 256;
    k_dag_flat<<<nblk, 256, 0, stream>>>(dag, pT, per_term, nparw, B, C, nseg);

    k_final<<<1, 256, 0, stream>>>(per_term, nparw, bce_part, NB1, out, B, C);
}

// Round 4
// 192.419 us; speedup vs baseline: 1.3890x; 1.0149x over previous
//
#include <hip/hip_runtime.h>
#include <math.h>

#define LAMBDA_DAG 0.5f

// -------- K1: probs (transposed) + BCE partials + zero accumulators --------
__global__ void k_probs_bce(const float* __restrict__ logits,
                            const float* __restrict__ labels,
                            float* __restrict__ pT,        // [C*B]
                            float* __restrict__ bce_part,  // [gridDim.x]
                            float* __restrict__ per_term,  // [C] -> zeroed
                            float* __restrict__ npar,      // [C] -> zeroed
                            int* __restrict__ edge_cnt,    // [1] -> zeroed
                            int B, int C) {
    const int N = B * C;
    const int stride = gridDim.x * blockDim.x;
    const int t0 = blockIdx.x * blockDim.x + threadIdx.x;

    if (t0 == 0) edge_cnt[0] = 0;
    for (int i = t0; i < C; i += stride) { per_term[i] = 0.f; npar[i] = 0.f; }

    float accv = 0.f;
    for (int idx = t0; idx < N; idx += stride) {
        float l = logits[idx];
        float y = labels[idx];
        accv += fmaxf(l, 0.f) + log1pf(expf(-fabsf(l))) - l * y;
        float p = 1.f / (1.f + expf(-l));
        int b = idx / C;
        int c = idx - b * C;
        pT[(size_t)c * B + b] = p;
    }
    __shared__ float sdata[256];
    sdata[threadIdx.x] = accv;
    __syncthreads();
    for (int s = blockDim.x >> 1; s > 0; s >>= 1) {
        if (threadIdx.x < s) sdata[threadIdx.x] += sdata[threadIdx.x + s];
        __syncthreads();
    }
    if (threadIdx.x == 0) bce_part[blockIdx.x] = sdata[0];
}

// -------- K2: pure dag stream -> compact edge list (no gathers here) --------
#define LBUF_CAP 2048
__global__ void __launch_bounds__(256) k_dag_scan(
        const float* __restrict__ dag, int CC,
        int* __restrict__ edge_buf, int* __restrict__ edge_cnt,
        int nseg) {
    __shared__ int lcnt, lbase;
    __shared__ int lbuf[LBUF_CAP];
    if (threadIdx.x == 0) lcnt = 0;
    __syncthreads();

    const int seg = blockIdx.x * blockDim.x + threadIdx.x;
    if (seg < nseg) {
        const int base = seg * 32;
        if (base + 32 <= CC) {
            const float4* dp = (const float4*)(dag + (size_t)base);
            float4 v[8];
#pragma unroll
            for (int h = 0; h < 8; ++h) v[h] = dp[h];   // 8 loads in flight
#pragma unroll
            for (int h = 0; h < 8; ++h) {
                float4 d4 = v[h];
                if (d4.x + d4.y + d4.z + d4.w > 0.f) {  // entries are 0/1
#pragma unroll
                    for (int k = 0; k < 4; ++k) {
                        float dv = (k == 0) ? d4.x : (k == 1) ? d4.y
                                 : (k == 2) ? d4.z : d4.w;
                        if (dv > 0.f) {
                            int slot = atomicAdd(&lcnt, 1);
                            if (slot < LBUF_CAP) lbuf[slot] = base + h * 4 + k;
                        }
                    }
                }
            }
        } else {                                        // generic tail
            for (int f = base; f < CC; ++f) {
                if (dag[f] > 0.f) {
                    int slot = atomicAdd(&lcnt, 1);
                    if (slot < LBUF_CAP) lbuf[slot] = f;
                }
            }
        }
    }
    __syncthreads();
    int n = min(lcnt, LBUF_CAP);
    if (threadIdx.x == 0) lbase = atomicAdd(edge_cnt, n);
    __syncthreads();
    for (int t = threadIdx.x; t < n; t += blockDim.x)
        edge_buf[lbase + t] = lbuf[t];
}

// -------- K3: one wave per edge, coalesced gather + shuffle reduce --------
__global__ void __launch_bounds__(256) k_edges(
        const int* __restrict__ edge_buf, const int* __restrict__ edge_cnt,
        const float* __restrict__ pT,
        float* __restrict__ per_term, float* __restrict__ npar,
        int B, int C) {
    const int lane = threadIdx.x & 63;
    const int wid = (blockIdx.x * blockDim.x + threadIdx.x) >> 6;
    const int nw = (gridDim.x * blockDim.x) >> 6;
    const int ne = edge_cnt[0];
    for (int e = wid; e < ne; e += nw) {
        int f = edge_buf[e];
        int i = f / C;
        int j = f - i * C;
        float s = 0.f;
        for (int b = lane; b < B; b += 64) {
            float diff = fmaxf(pT[(size_t)i * B + b] - pT[(size_t)j * B + b], 0.f);
            s += diff * diff;
        }
#pragma unroll
        for (int off = 32; off > 0; off >>= 1)
            s += __shfl_down(s, off, 64);
        if (lane == 0) {
            atomicAdd(&per_term[i], s);
            atomicAdd(&npar[i], 1.f);
        }
    }
}

// -------- K4: final scalar reduction --------
__global__ void k_final(const float* __restrict__ per_term,
                        const float* __restrict__ npar,
                        const float* __restrict__ bce_part, int nb,
                        float* __restrict__ out, int B, int C) {
    float bs = 0.f, ps = 0.f, es = 0.f;
    for (int k = threadIdx.x; k < nb; k += blockDim.x) bs += bce_part[k];
    for (int i = threadIdx.x; i < C; i += blockDim.x) {
        float np = npar[i];
        es += np;
        if (np > 0.f) ps += per_term[i] / ((float)B * np);
    }
    __shared__ float s1[256], s2[256], s3[256];
    s1[threadIdx.x] = bs;
    s2[threadIdx.x] = ps;
    s3[threadIdx.x] = es;
    __syncthreads();
    for (int s = blockDim.x >> 1; s > 0; s >>= 1) {
        if (threadIdx.x < s) {
            s1[threadIdx.x] += s1[threadIdx.x + s];
            s2[threadIdx.x] += s2[threadIdx.x + s];
            s3[threadIdx.x] += s3[threadIdx.x + s];
        }
        __syncthreads();
    }
    if (threadIdx.x == 0) {
        float penalty = (s3[0] > 0.f) ? (s2[0] / s3[0]) : 0.f;
        out[0] = s1[0] / (float)(B * C) + LAMBDA_DAG * penalty;
    }
}

extern "C" void kernel_launch(void* const* d_in, const int* in_sizes, int n_in,
                              void* d_out, int out_size, void* d_ws, size_t ws_size,
                              hipStream_t stream) {
    const float* logits = (const float*)d_in[0];
    const float* labels = (const float*)d_in[1];
    const float* dag    = (const float*)d_in[2];
    float* out = (float*)d_out;

    const int C  = (int)(sqrt((double)in_sizes[2]) + 0.5);
    const int B  = in_sizes[0] / C;
    const int CC = in_sizes[2];

    float* ws       = (float*)d_ws;
    float* pT       = ws;                          // C*B floats (16B-aligned)
    float* per_term = pT + (size_t)C * B;          // C
    float* nparw    = per_term + C;                // C
    float* bce_part = nparw + C;                   // NB1
    const int NB1 = 320;
    int* edge_cnt   = (int*)(bce_part + NB1);      // 1 (+3 pad)
    int* edge_buf   = edge_cnt + 4;                // up to 1M edges

    k_probs_bce<<<NB1, 256, 0, stream>>>(logits, labels, pT, bce_part,
                                         per_term, nparw, edge_cnt, B, C);

    const int nseg = (CC + 31) / 32;               // 781250 for C=5000
    const int nblk = (nseg + 255) / 256;
    k_dag_scan<<<nblk, 256, 0, stream>>>(dag, CC, edge_buf, edge_cnt, nseg);

    k_edges<<<512, 256, 0, stream>>>(edge_buf, edge_cnt, pT, per_term, nparw, B, C);

    k_final<<<1, 256, 0, stream>>>(per_term, nparw, bce_part, NB1, out, B, C);
}